// Round 1
// baseline (788.132 us; speedup 1.0000x reference)
//
#include <hip/hip_runtime.h>
#include <math.h>

// Problem constants
#define B_ 8
#define N_ 5000
#define E_ 160000
#define M_ 40000      // N_*B_ rows, r = n*B_ + b
#define K_ 512

typedef __bf16 v8bf __attribute__((ext_vector_type(8)));
typedef float  v4f  __attribute__((ext_vector_type(4)));
typedef unsigned short u16x4v __attribute__((ext_vector_type(4)));

__device__ __forceinline__ unsigned short f2b(float f){
  unsigned int u = __builtin_bit_cast(unsigned int, f);
  u += 0x7FFFu + ((u >> 16) & 1u);          // round-to-nearest-even
  return (unsigned short)(u >> 16);
}
__device__ __forceinline__ float b2f(unsigned short s){
  return __builtin_bit_cast(float, ((unsigned int)s) << 16);
}
__device__ __forceinline__ float softplus_(float x){
  return (x > 15.0f) ? x : log1pf(__expf(x));
}

// ---------------- setup kernels ----------------

__global__ __launch_bounds__(256) void zero_int2(int* a, int* b, int n){
  int i = blockIdx.x*256 + threadIdx.x;
  if (i < n){ a[i] = 0; b[i] = 0; }
}

// 5 * 131072 elements; m selects matrix. dest: 0->WA, 1..3->Wcat rows [Fc;Gc;Z], 4->WFh
__global__ __launch_bounds__(256) void convert_weights(
    const float* __restrict__ wA, const float* __restrict__ wFc,
    const float* __restrict__ wGc, const float* __restrict__ wZ,
    const float* __restrict__ wFh,
    unsigned short* __restrict__ WA, unsigned short* __restrict__ Wcat,
    unsigned short* __restrict__ WFh)
{
  int idx = blockIdx.x*256 + threadIdx.x;      // < 655360
  int m = idx >> 17;                           // 131072 = 2^17
  int i = idx & 131071;
  float v;
  if      (m == 0) v = wA[i];
  else if (m == 1) v = wFc[i];
  else if (m == 2) v = wGc[i];
  else if (m == 3) v = wZ[i];
  else             v = wFh[i];
  unsigned short o = f2b(v);
  if      (m == 0) WA[i] = o;
  else if (m == 4) WFh[i] = o;
  else             Wcat[(m-1)*131072 + i] = o;
}

// u (B,N,512) fp32 -> cB[r*256+q] bf16 (c part), hT[r*256+q] bf16 (h part), r=n*B+b
__global__ __launch_bounds__(256) void convert_u(
    const float* __restrict__ u, unsigned short* __restrict__ cB,
    unsigned short* __restrict__ hT)
{
  int r = blockIdx.x*4 + (threadIdx.x >> 6);
  int l = threadIdx.x & 63;
  int n = r >> 3, b = r & 7;
  const float* up = u + (size_t)(b*N_ + n)*512 + l*4;
  float4 cf = *(const float4*)up;
  float4 hf = *(const float4*)(up + 256);
  u16x4v c4, h4;
  c4.x = f2b(cf.x); c4.y = f2b(cf.y); c4.z = f2b(cf.z); c4.w = f2b(cf.w);
  h4.x = f2b(hf.x); h4.y = f2b(hf.y); h4.z = f2b(hf.z); h4.w = f2b(hf.w);
  *(u16x4v*)(cB + (size_t)r*256 + l*4) = c4;
  *(u16x4v*)(hT + (size_t)r*256 + l*4) = h4;
}

// ---------------- CSR build ----------------

__global__ __launch_bounds__(256) void hist_kernel(const int* __restrict__ dst, int* __restrict__ deg){
  int e = blockIdx.x*256 + threadIdx.x;   // exactly E_
  atomicAdd(&deg[dst[e]], 1);
}

__global__ __launch_bounds__(256) void scan_kernel(
    const int* __restrict__ deg, int* __restrict__ row_start, float* __restrict__ inv_deg)
{
  __shared__ int sums[256];
  int t = threadIdx.x;
  int base = t*20;
  int cnt[20];
  int local = 0;
#pragma unroll
  for (int i = 0; i < 20; ++i){
    int n = base + i;
    int d = (n < N_) ? deg[n] : 0;
    cnt[i] = d; local += d;
  }
  sums[t] = local; __syncthreads();
  for (int s = 1; s < 256; s <<= 1){
    int v = (t >= s) ? sums[t - s] : 0;
    __syncthreads();
    sums[t] += v;
    __syncthreads();
  }
  int prefix = (t == 0) ? 0 : sums[t-1];
#pragma unroll
  for (int i = 0; i < 20; ++i){
    int n = base + i;
    if (n < N_){
      row_start[n] = prefix;
      int d = cnt[i];
      inv_deg[n] = 1.0f / (float)((d > 1) ? d : 1);
      prefix += d;
    }
  }
  if (t == 255) row_start[N_] = prefix;
}

__global__ __launch_bounds__(256) void fill_kernel(
    const int* __restrict__ src, const int* __restrict__ dst,
    const int* __restrict__ row_start, int* __restrict__ cursor, int* __restrict__ csr)
{
  int e = blockIdx.x*256 + threadIdx.x;
  int d = dst[e];
  int p = atomicAdd(&cursor[d], 1);
  csr[row_start[d] + p] = src[e];
}

// one wave per r=(n,b): agg[r,q] = mean over edges dst==n of h[b,src,q]
__global__ __launch_bounds__(256) void gather_kernel(
    const unsigned short* __restrict__ hT, const int* __restrict__ csr,
    const int* __restrict__ row_start, const float* __restrict__ inv_deg,
    unsigned short* __restrict__ aggT)
{
  int r = blockIdx.x*4 + (threadIdx.x >> 6);
  int l = threadIdx.x & 63;
  int n = r >> 3, b = r & 7;
  int e0 = row_start[n], e1 = row_start[n+1];
  float a0 = 0.f, a1 = 0.f, a2 = 0.f, a3 = 0.f;
  const unsigned short* base = hT + b*256 + l*4;
  for (int e = e0; e < e1; ++e){
    int s = csr[e];
    u16x4v hv = *(const u16x4v*)(base + (size_t)s*2048);
    a0 += b2f(hv.x); a1 += b2f(hv.y); a2 += b2f(hv.z); a3 += b2f(hv.w);
  }
  float inv = inv_deg[n];
  u16x4v o;
  o.x = f2b(a0*inv); o.y = f2b(a1*inv); o.z = f2b(a2*inv); o.w = f2b(a3*inv);
  *(u16x4v*)(aggT + (size_t)r*256 + l*4) = o;
}

// ---------------- GEMM 1: h_ = softplus([h|agg] @ W_A^T + b_A) ----------------
// block: 64 rows x 256 cols, 4 waves, wave = 64 rows x 64 cols (4x4 frags)

__global__ __launch_bounds__(256) void gemm1_kernel(
    const unsigned short* __restrict__ hT, const unsigned short* __restrict__ aggT,
    const unsigned short* __restrict__ WA, const float* __restrict__ bA,
    unsigned short* __restrict__ hB)
{
  const int tid = threadIdx.x;
  const int w = tid >> 6, l = tid & 63, lq = l >> 4, lr = l & 15;
  const int m0 = blockIdx.x * 64;
  const int n0 = w * 64;

  int aOff[4], bOff[4];
#pragma unroll
  for (int rt = 0; rt < 4; ++rt) aOff[rt] = (m0 + rt*16 + lr)*256 + lq*8;
#pragma unroll
  for (int ct = 0; ct < 4; ++ct) bOff[ct] = (n0 + ct*16 + lr)*512 + lq*8;

  v4f acc[4][4] = {};
#pragma unroll
  for (int k = 0; k < 16; ++k){
    const unsigned short* Ab = (k < 8) ? hT : aggT;
    const int kk = (k & 7) * 32;
    v8bf a[4], bf[4];
#pragma unroll
    for (int rt = 0; rt < 4; ++rt) a[rt] = *(const v8bf*)(Ab + aOff[rt] + kk);
#pragma unroll
    for (int ct = 0; ct < 4; ++ct) bf[ct] = *(const v8bf*)(WA + bOff[ct] + k*32);
#pragma unroll
    for (int rt = 0; rt < 4; ++rt)
#pragma unroll
      for (int ct = 0; ct < 4; ++ct)
        acc[rt][ct] = __builtin_amdgcn_mfma_f32_16x16x32_bf16(a[rt], bf[ct], acc[rt][ct], 0, 0, 0);
  }

#pragma unroll
  for (int ct = 0; ct < 4; ++ct){
    const int col = n0 + ct*16 + lr;
    const float bias = bA[col];
#pragma unroll
    for (int rt = 0; rt < 4; ++rt){
#pragma unroll
      for (int reg = 0; reg < 4; ++reg){
        const int grow = m0 + rt*16 + lq*4 + reg;
        hB[(size_t)grow*256 + col] = f2b(softplus_(acc[rt][ct][reg] + bias));
      }
    }
  }
}

// ---------------- GEMM 2a: Fc,Gc,Z -> dc with projection ----------------
// block: 64 rows x 768 cols, 12 waves: wave w -> matrix mg=w>>2, col group cg=w&3

__global__ __launch_bounds__(768, 3) void gemm2a_kernel(
    const unsigned short* __restrict__ cB, const unsigned short* __restrict__ hB,
    const unsigned short* __restrict__ Wcat,
    const float* __restrict__ bFc, const float* __restrict__ bGc, const float* __restrict__ bZ,
    const float* __restrict__ u, float* __restrict__ out)
{
  __shared__ float ldsG[16*256];
  __shared__ float ldsZ[16*256];
  __shared__ float redN[4][16];
  __shared__ float redD[4][16];

  const int tid = threadIdx.x;
  const int w = tid >> 6;       // 0..11
  const int mg = w >> 2;        // 0=Fc, 1=Gc, 2=Z
  const int cg = w & 3;
  const int l = tid & 63, lq = l >> 4, lr = l & 15;
  const int m0 = blockIdx.x * 64;

  int aOff[4], bOff[4];
#pragma unroll
  for (int rt = 0; rt < 4; ++rt) aOff[rt] = (m0 + rt*16 + lr)*256 + lq*8;
#pragma unroll
  for (int ct = 0; ct < 4; ++ct) bOff[ct] = (mg*256 + cg*64 + ct*16 + lr)*512 + lq*8;

  v4f acc[4][4] = {};
#pragma unroll
  for (int k = 0; k < 16; ++k){
    const unsigned short* Ab = (k < 8) ? cB : hB;
    const int kk = (k & 7) * 32;
    v8bf a[4], bf[4];
#pragma unroll
    for (int rt = 0; rt < 4; ++rt) a[rt] = *(const v8bf*)(Ab + aOff[rt] + kk);
#pragma unroll
    for (int ct = 0; ct < 4; ++ct) bf[ct] = *(const v8bf*)(Wcat + bOff[ct] + k*32);
#pragma unroll
    for (int rt = 0; rt < 4; ++rt)
#pragma unroll
      for (int ct = 0; ct < 4; ++ct)
        acc[rt][ct] = __builtin_amdgcn_mfma_f32_16x16x32_bf16(a[rt], bf[ct], acc[rt][ct], 0, 0, 0);
  }

  const float* bias = (mg == 0) ? bFc : (mg == 1) ? bGc : bZ;
  float bv[4];
#pragma unroll
  for (int ct = 0; ct < 4; ++ct) bv[ct] = bias[cg*64 + ct*16 + lr];

  // phased epilogue: 16 rows (one row-tile) at a time to fit LDS
  for (int p = 0; p < 4; ++p){
    if (mg == 1){
#pragma unroll
      for (int ct = 0; ct < 4; ++ct)
#pragma unroll
        for (int reg = 0; reg < 4; ++reg)
          ldsG[(lq*4+reg)*256 + cg*64 + ct*16 + lr] = softplus_(acc[p][ct][reg] + bv[ct]);
    } else if (mg == 2){
#pragma unroll
      for (int ct = 0; ct < 4; ++ct)
#pragma unroll
        for (int reg = 0; reg < 4; ++reg)
          ldsZ[(lq*4+reg)*256 + cg*64 + ct*16 + lr] = tanhf(acc[p][ct][reg] + bv[ct]);
    }
    __syncthreads();

    float dcv[4][4], cv[4][4];
    float num[4] = {0.f,0.f,0.f,0.f}, den[4] = {0.f,0.f,0.f,0.f};
    if (mg == 0){
#pragma unroll
      for (int ct = 0; ct < 4; ++ct){
        const int col = cg*64 + ct*16 + lr;
#pragma unroll
        for (int reg = 0; reg < 4; ++reg){
          const int r = m0 + p*16 + lq*4 + reg;
          const int n = r >> 3, b = r & 7;
          const float c = u[(size_t)(b*N_ + n)*512 + col];
          const float fc = softplus_(acc[p][ct][reg] + bv[ct]);
          const float g  = ldsG[(lq*4+reg)*256 + col];
          const float z  = ldsZ[(lq*4+reg)*256 + col];
          const float dc = -fc*c + g*z;
          dcv[ct][reg] = dc; cv[ct][reg] = c;
          num[reg] += dc*c; den[reg] += c*c;
        }
      }
#pragma unroll
      for (int reg = 0; reg < 4; ++reg){
#pragma unroll
        for (int s = 1; s < 16; s <<= 1){
          num[reg] += __shfl_xor(num[reg], s, 64);
          den[reg] += __shfl_xor(den[reg], s, 64);
        }
        if (lr == 0){ redN[cg][lq*4+reg] = num[reg]; redD[cg][lq*4+reg] = den[reg]; }
      }
    }
    __syncthreads();

    if (mg == 0){
#pragma unroll
      for (int ct = 0; ct < 4; ++ct){
        const int col = cg*64 + ct*16 + lr;
#pragma unroll
        for (int reg = 0; reg < 4; ++reg){
          const int rip = lq*4 + reg;
          const float tn = redN[0][rip] + redN[1][rip] + redN[2][rip] + redN[3][rip];
          const float td = redD[0][rip] + redD[1][rip] + redD[2][rip] + redD[3][rip];
          const float proj = tn / td;
          const int r = m0 + p*16 + rip;
          const int n = r >> 3, b = r & 7;
          out[(size_t)(b*N_ + n)*512 + col] = dcv[ct][reg] - proj*cv[ct][reg];
        }
      }
    }
    __syncthreads();
  }
}

// ---------------- GEMM 2b: dh = -softplus(Fh) * h ----------------

__global__ __launch_bounds__(256) void gemm2b_kernel(
    const unsigned short* __restrict__ cB, const unsigned short* __restrict__ hB,
    const unsigned short* __restrict__ WFh, const float* __restrict__ bFh,
    const float* __restrict__ u, float* __restrict__ out)
{
  const int tid = threadIdx.x;
  const int w = tid >> 6, l = tid & 63, lq = l >> 4, lr = l & 15;
  const int m0 = blockIdx.x * 64;
  const int n0 = w * 64;

  int aOff[4], bOff[4];
#pragma unroll
  for (int rt = 0; rt < 4; ++rt) aOff[rt] = (m0 + rt*16 + lr)*256 + lq*8;
#pragma unroll
  for (int ct = 0; ct < 4; ++ct) bOff[ct] = (n0 + ct*16 + lr)*512 + lq*8;

  v4f acc[4][4] = {};
#pragma unroll
  for (int k = 0; k < 16; ++k){
    const unsigned short* Ab = (k < 8) ? cB : hB;
    const int kk = (k & 7) * 32;
    v8bf a[4], bf[4];
#pragma unroll
    for (int rt = 0; rt < 4; ++rt) a[rt] = *(const v8bf*)(Ab + aOff[rt] + kk);
#pragma unroll
    for (int ct = 0; ct < 4; ++ct) bf[ct] = *(const v8bf*)(WFh + bOff[ct] + k*32);
#pragma unroll
    for (int rt = 0; rt < 4; ++rt)
#pragma unroll
      for (int ct = 0; ct < 4; ++ct)
        acc[rt][ct] = __builtin_amdgcn_mfma_f32_16x16x32_bf16(a[rt], bf[ct], acc[rt][ct], 0, 0, 0);
  }

#pragma unroll
  for (int ct = 0; ct < 4; ++ct){
    const int col = n0 + ct*16 + lr;
    const float bias = bFh[col];
#pragma unroll
    for (int rt = 0; rt < 4; ++rt){
#pragma unroll
      for (int reg = 0; reg < 4; ++reg){
        const int r = m0 + rt*16 + lq*4 + reg;
        const int n = r >> 3, b = r & 7;
        const size_t idx = (size_t)(b*N_ + n)*512 + 256 + col;
        const float h = u[idx];
        out[idx] = -softplus_(acc[rt][ct][reg] + bias) * h;
      }
    }
  }
}

// ---------------- launch ----------------

extern "C" void kernel_launch(void* const* d_in, const int* in_sizes, int n_in,
                              void* d_out, int out_size, void* d_ws, size_t ws_size,
                              hipStream_t stream) {
  const float* u    = (const float*)d_in[0];
  const int*   src  = (const int*)d_in[1];
  const int*   dst  = (const int*)d_in[2];
  const float* wFc  = (const float*)d_in[4];
  const float* bFc  = (const float*)d_in[5];
  const float* wFh  = (const float*)d_in[6];
  const float* bFh  = (const float*)d_in[7];
  const float* wGc  = (const float*)d_in[8];
  const float* bGc  = (const float*)d_in[9];
  const float* wZ   = (const float*)d_in[10];
  const float* bZ   = (const float*)d_in[11];
  const float* wA   = (const float*)d_in[12];
  const float* bA   = (const float*)d_in[13];
  float* out = (float*)d_out;

  char* W = (char*)d_ws;
  unsigned short* hT   = (unsigned short*)(W + 0);           // 20,480,000 B
  unsigned short* cB   = (unsigned short*)(W + 20480000);
  unsigned short* aggT = (unsigned short*)(W + 40960000);
  unsigned short* hB   = (unsigned short*)(W + 61440000);
  unsigned short* WA   = (unsigned short*)(W + 81920000);    // 262,144 B
  unsigned short* Wcat = (unsigned short*)(W + 82182144);    // 786,432 B
  unsigned short* WFh  = (unsigned short*)(W + 82968576);    // 262,144 B
  int* deg       = (int*)(W + 83230720);
  int* row_start = (int*)(W + 83250944);
  int* cursor    = (int*)(W + 83271168);
  int* csr       = (int*)(W + 83291392);
  float* inv_deg = (float*)(W + 83931392);

  zero_int2<<<(N_ + 255)/256, 256, 0, stream>>>(deg, cursor, N_);
  convert_weights<<<2560, 256, 0, stream>>>(wA, wFc, wGc, wZ, wFh, WA, Wcat, WFh);
  convert_u<<<M_/4, 256, 0, stream>>>(u, cB, hT);
  hist_kernel<<<E_/256, 256, 0, stream>>>(dst, deg);
  scan_kernel<<<1, 256, 0, stream>>>(deg, row_start, inv_deg);
  fill_kernel<<<E_/256, 256, 0, stream>>>(src, dst, row_start, cursor, csr);
  gather_kernel<<<M_/4, 256, 0, stream>>>(hT, csr, row_start, inv_deg, aggT);
  gemm1_kernel<<<M_/64, 256, 0, stream>>>(hT, aggT, WA, bA, hB);
  gemm2a_kernel<<<M_/64, 768, 0, stream>>>(cB, hB, Wcat, bFc, bGc, bZ, u, out);
  gemm2b_kernel<<<M_/64, 256, 0, stream>>>(cB, hB, WFh, bFh, u, out);
}

// Round 2
// 680.186 us; speedup vs baseline: 1.1587x; 1.1587x over previous
//
#include <hip/hip_runtime.h>
#include <math.h>

// Problem constants
#define B_ 8
#define N_ 5000
#define E_ 160000
#define M_ 40000      // N_*B_ rows, r = n*B_ + b
#define K_ 512

typedef __bf16 v8bf __attribute__((ext_vector_type(8)));
typedef float  v4f  __attribute__((ext_vector_type(4)));
typedef unsigned short u16x4v __attribute__((ext_vector_type(4)));

__device__ __forceinline__ unsigned short f2b(float f){
  unsigned int u = __builtin_bit_cast(unsigned int, f);
  u += 0x7FFFu + ((u >> 16) & 1u);          // round-to-nearest-even
  return (unsigned short)(u >> 16);
}
__device__ __forceinline__ float b2f(unsigned short s){
  return __builtin_bit_cast(float, ((unsigned int)s) << 16);
}
__device__ __forceinline__ float softplus_(float x){
  return (x > 15.0f) ? x : log1pf(__expf(x));
}

// ---------------- setup kernels ----------------

__global__ __launch_bounds__(256) void zero_int2(int* a, int* b, int n){
  int i = blockIdx.x*256 + threadIdx.x;
  if (i < n){ a[i] = 0; b[i] = 0; }
}

// 5 * 131072 weight elems + 1024 packed bias. m: 0->WA, 1..4->Wall rows [Fc;Gc;Z;Fh]
__global__ __launch_bounds__(256) void convert_weights(
    const float* __restrict__ wA, const float* __restrict__ wFc,
    const float* __restrict__ wGc, const float* __restrict__ wZ,
    const float* __restrict__ wFh,
    const float* __restrict__ bFc, const float* __restrict__ bGc,
    const float* __restrict__ bZ,  const float* __restrict__ bFh,
    unsigned short* __restrict__ WA, unsigned short* __restrict__ Wall,
    float* __restrict__ biasP)
{
  int idx = blockIdx.x*256 + threadIdx.x;      // < 656384
  if (idx >= 655360){
    int j = idx - 655360;                      // 0..1023
    int mat = j >> 8, jj = j & 255;
    const float* bp = (mat == 0) ? bFc : (mat == 1) ? bGc : (mat == 2) ? bZ : bFh;
    biasP[j] = bp[jj];
    return;
  }
  int m = idx >> 17;                           // 131072 = 2^17
  int i = idx & 131071;
  float v;
  if      (m == 0) v = wA[i];
  else if (m == 1) v = wFc[i];
  else if (m == 2) v = wGc[i];
  else if (m == 3) v = wZ[i];
  else             v = wFh[i];
  unsigned short o = f2b(v);
  if (m == 0) WA[i] = o;
  else        Wall[(m-1)*131072 + i] = o;
}

// u (B,N,512) fp32 -> cB[r*256+q] bf16 (c part), hT[r*256+q] bf16 (h part), r=n*B+b
__global__ __launch_bounds__(256) void convert_u(
    const float* __restrict__ u, unsigned short* __restrict__ cB,
    unsigned short* __restrict__ hT)
{
  int r = blockIdx.x*4 + (threadIdx.x >> 6);
  int l = threadIdx.x & 63;
  int n = r >> 3, b = r & 7;
  const float* up = u + (size_t)(b*N_ + n)*512 + l*4;
  float4 cf = *(const float4*)up;
  float4 hf = *(const float4*)(up + 256);
  u16x4v c4, h4;
  c4.x = f2b(cf.x); c4.y = f2b(cf.y); c4.z = f2b(cf.z); c4.w = f2b(cf.w);
  h4.x = f2b(hf.x); h4.y = f2b(hf.y); h4.z = f2b(hf.z); h4.w = f2b(hf.w);
  *(u16x4v*)(cB + (size_t)r*256 + l*4) = c4;
  *(u16x4v*)(hT + (size_t)r*256 + l*4) = h4;
}

// ---------------- CSR build ----------------

__global__ __launch_bounds__(256) void hist_kernel(const int* __restrict__ dst, int* __restrict__ deg){
  int e = blockIdx.x*256 + threadIdx.x;   // exactly E_
  atomicAdd(&deg[dst[e]], 1);
}

__global__ __launch_bounds__(256) void scan_kernel(
    const int* __restrict__ deg, int* __restrict__ row_start, float* __restrict__ inv_deg)
{
  __shared__ int sums[256];
  int t = threadIdx.x;
  int base = t*20;
  int cnt[20];
  int local = 0;
#pragma unroll
  for (int i = 0; i < 20; ++i){
    int n = base + i;
    int d = (n < N_) ? deg[n] : 0;
    cnt[i] = d; local += d;
  }
  sums[t] = local; __syncthreads();
  for (int s = 1; s < 256; s <<= 1){
    int v = (t >= s) ? sums[t - s] : 0;
    __syncthreads();
    sums[t] += v;
    __syncthreads();
  }
  int prefix = (t == 0) ? 0 : sums[t-1];
#pragma unroll
  for (int i = 0; i < 20; ++i){
    int n = base + i;
    if (n < N_){
      row_start[n] = prefix;
      int d = cnt[i];
      inv_deg[n] = 1.0f / (float)((d > 1) ? d : 1);
      prefix += d;
    }
  }
  if (t == 255) row_start[N_] = prefix;
}

__global__ __launch_bounds__(256) void fill_kernel(
    const int* __restrict__ src, const int* __restrict__ dst,
    const int* __restrict__ row_start, int* __restrict__ cursor, int* __restrict__ csr)
{
  int e = blockIdx.x*256 + threadIdx.x;
  int d = dst[e];
  int p = atomicAdd(&cursor[d], 1);
  csr[row_start[d] + p] = src[e];
}

// one wave per r=(n,b): agg[r,q] = mean over edges dst==n of h[b,src,q]
__global__ __launch_bounds__(256) void gather_kernel(
    const unsigned short* __restrict__ hT, const int* __restrict__ csr,
    const int* __restrict__ row_start, const float* __restrict__ inv_deg,
    unsigned short* __restrict__ aggT)
{
  int r = blockIdx.x*4 + (threadIdx.x >> 6);
  int l = threadIdx.x & 63;
  int n = r >> 3, b = r & 7;
  int e0 = row_start[n], e1 = row_start[n+1];
  float a0 = 0.f, a1 = 0.f, a2 = 0.f, a3 = 0.f;
  const unsigned short* base = hT + b*256 + l*4;
  for (int e = e0; e < e1; ++e){
    int s = csr[e];
    u16x4v hv = *(const u16x4v*)(base + (size_t)s*2048);
    a0 += b2f(hv.x); a1 += b2f(hv.y); a2 += b2f(hv.z); a3 += b2f(hv.w);
  }
  float inv = inv_deg[n];
  u16x4v o;
  o.x = f2b(a0*inv); o.y = f2b(a1*inv); o.z = f2b(a2*inv); o.w = f2b(a3*inv);
  *(u16x4v*)(aggT + (size_t)r*256 + l*4) = o;
}

// ---------------- GEMM 1: h_ = softplus([h|agg] @ W_A^T + b_A) ----------------
// block: 64 rows x 256 cols, 4 waves, wave = 64 rows x 64 cols (4x4 frags)

__global__ __launch_bounds__(256) void gemm1_kernel(
    const unsigned short* __restrict__ hT, const unsigned short* __restrict__ aggT,
    const unsigned short* __restrict__ WA, const float* __restrict__ bA,
    unsigned short* __restrict__ hB)
{
  const int tid = threadIdx.x;
  const int w = tid >> 6, l = tid & 63, lq = l >> 4, lr = l & 15;
  const int m0 = blockIdx.x * 64;
  const int n0 = w * 64;

  int aOff[4], bOff[4];
#pragma unroll
  for (int rt = 0; rt < 4; ++rt) aOff[rt] = (m0 + rt*16 + lr)*256 + lq*8;
#pragma unroll
  for (int ct = 0; ct < 4; ++ct) bOff[ct] = (n0 + ct*16 + lr)*512 + lq*8;

  v4f acc[4][4] = {};
#pragma unroll
  for (int k = 0; k < 16; ++k){
    const unsigned short* Ab = (k < 8) ? hT : aggT;
    const int kk = (k & 7) * 32;
    v8bf a[4], bf[4];
#pragma unroll
    for (int rt = 0; rt < 4; ++rt) a[rt] = *(const v8bf*)(Ab + aOff[rt] + kk);
#pragma unroll
    for (int ct = 0; ct < 4; ++ct) bf[ct] = *(const v8bf*)(WA + bOff[ct] + k*32);
#pragma unroll
    for (int rt = 0; rt < 4; ++rt)
#pragma unroll
      for (int ct = 0; ct < 4; ++ct)
        acc[rt][ct] = __builtin_amdgcn_mfma_f32_16x16x32_bf16(a[rt], bf[ct], acc[rt][ct], 0, 0, 0);
  }

#pragma unroll
  for (int ct = 0; ct < 4; ++ct){
    const int col = n0 + ct*16 + lr;
    const float bias = bA[col];
#pragma unroll
    for (int rt = 0; rt < 4; ++rt){
#pragma unroll
      for (int reg = 0; reg < 4; ++reg){
        const int grow = m0 + rt*16 + lq*4 + reg;
        hB[(size_t)grow*256 + col] = f2b(softplus_(acc[rt][ct][reg] + bias));
      }
    }
  }
}

// ---------------- GEMM big: act = activation([c|h_] @ Wall^T + biasP) ----------------
// Wall rows: [W_Fc(0:256); W_Gc(256:512); W_Z(512:768); W_Fh(768:1024)], K=512.
// act stored bf16 into d_out: row rr=b*N+n occupies out row rr's 2048 bytes.
// grid (M/64, 4): blockIdx.y selects 256-col slab (= one matrix), wave w = 64 cols.

__global__ __launch_bounds__(256) void gemm_big_kernel(
    const unsigned short* __restrict__ cB, const unsigned short* __restrict__ hB,
    const unsigned short* __restrict__ Wall, const float* __restrict__ biasP,
    unsigned short* __restrict__ act)
{
  const int tid = threadIdx.x;
  const int w = tid >> 6, l = tid & 63, lq = l >> 4, lr = l & 15;
  const int m0 = blockIdx.x * 64;
  const int n0 = blockIdx.y * 256 + w * 64;
  const bool is_tanh = (blockIdx.y == 2);

  int aOff[4], bOff[4];
#pragma unroll
  for (int rt = 0; rt < 4; ++rt) aOff[rt] = (m0 + rt*16 + lr)*256 + lq*8;
#pragma unroll
  for (int ct = 0; ct < 4; ++ct) bOff[ct] = (n0 + ct*16 + lr)*512 + lq*8;

  v4f acc[4][4] = {};
#pragma unroll
  for (int k = 0; k < 16; ++k){
    const unsigned short* Ab = (k < 8) ? cB : hB;
    const int kk = (k & 7) * 32;
    v8bf a[4], bf[4];
#pragma unroll
    for (int rt = 0; rt < 4; ++rt) a[rt] = *(const v8bf*)(Ab + aOff[rt] + kk);
#pragma unroll
    for (int ct = 0; ct < 4; ++ct) bf[ct] = *(const v8bf*)(Wall + bOff[ct] + k*32);
#pragma unroll
    for (int rt = 0; rt < 4; ++rt)
#pragma unroll
      for (int ct = 0; ct < 4; ++ct)
        acc[rt][ct] = __builtin_amdgcn_mfma_f32_16x16x32_bf16(a[rt], bf[ct], acc[rt][ct], 0, 0, 0);
  }

#pragma unroll
  for (int ct = 0; ct < 4; ++ct){
    const int col = n0 + ct*16 + lr;
    const float bias = biasP[col];
#pragma unroll
    for (int rt = 0; rt < 4; ++rt){
#pragma unroll
      for (int reg = 0; reg < 4; ++reg){
        const int r = m0 + rt*16 + lq*4 + reg;
        const int n = r >> 3, b = r & 7;
        const int rr = b*N_ + n;
        const float x = acc[rt][ct][reg] + bias;
        const float v = is_tanh ? tanhf(x) : softplus_(x);
        act[(size_t)rr*1024 + col] = f2b(v);
      }
    }
  }
}

// ---------------- epilogue: dc with projection + dh ----------------
// One wave per row r. act aliases out (same row region) — reads complete before
// stores within the wave; no __restrict__ so the compiler keeps the order.

__global__ __launch_bounds__(256) void epilogue_kernel(
    const unsigned short* act, const float* __restrict__ u, float* out)
{
  int r = blockIdx.x*4 + (threadIdx.x >> 6);
  int l = threadIdx.x & 63;
  int n = r >> 3, b = r & 7;
  const size_t rr = (size_t)(b*N_ + n);
  const unsigned short* arow = act + rr*1024;
  const float* urow = u + rr*512;
  float* orow = out + rr*512;

  u16x4v fc4 = *(const u16x4v*)(arow +        l*4);
  u16x4v gc4 = *(const u16x4v*)(arow + 256 +  l*4);
  u16x4v z4  = *(const u16x4v*)(arow + 512 +  l*4);
  u16x4v fh4 = *(const u16x4v*)(arow + 768 +  l*4);
  float4 c4f = *(const float4*)(urow + l*4);
  float4 h4f = *(const float4*)(urow + 256 + l*4);

  float c[4] = {c4f.x, c4f.y, c4f.z, c4f.w};
  float h[4] = {h4f.x, h4f.y, h4f.z, h4f.w};
  float dc[4], fh[4];
  float num = 0.f, den = 0.f;
#pragma unroll
  for (int i = 0; i < 4; ++i){
    float fc = b2f(fc4[i]), gc = b2f(gc4[i]), z = b2f(z4[i]);
    fh[i] = b2f(fh4[i]);
    dc[i] = -fc*c[i] + gc*z;
    num += dc[i]*c[i];
    den += c[i]*c[i];
  }
#pragma unroll
  for (int s = 1; s < 64; s <<= 1){
    num += __shfl_xor(num, s, 64);
    den += __shfl_xor(den, s, 64);
  }
  const float proj = num / den;

  float4 o, oh;
  o.x = dc[0] - proj*c[0]; o.y = dc[1] - proj*c[1];
  o.z = dc[2] - proj*c[2]; o.w = dc[3] - proj*c[3];
  oh.x = -fh[0]*h[0]; oh.y = -fh[1]*h[1];
  oh.z = -fh[2]*h[2]; oh.w = -fh[3]*h[3];
  *(float4*)(orow + l*4) = o;
  *(float4*)(orow + 256 + l*4) = oh;
}

// ---------------- launch ----------------

extern "C" void kernel_launch(void* const* d_in, const int* in_sizes, int n_in,
                              void* d_out, int out_size, void* d_ws, size_t ws_size,
                              hipStream_t stream) {
  const float* u    = (const float*)d_in[0];
  const int*   src  = (const int*)d_in[1];
  const int*   dst  = (const int*)d_in[2];
  const float* wFc  = (const float*)d_in[4];
  const float* bFc  = (const float*)d_in[5];
  const float* wFh  = (const float*)d_in[6];
  const float* bFh  = (const float*)d_in[7];
  const float* wGc  = (const float*)d_in[8];
  const float* bGc  = (const float*)d_in[9];
  const float* wZ   = (const float*)d_in[10];
  const float* bZ   = (const float*)d_in[11];
  const float* wA   = (const float*)d_in[12];
  const float* bA   = (const float*)d_in[13];
  float* out = (float*)d_out;
  unsigned short* act = (unsigned short*)d_out;   // bf16 activations overlay out

  char* W = (char*)d_ws;
  unsigned short* hT   = (unsigned short*)(W + 0);           // 20,480,000 B
  unsigned short* cB   = (unsigned short*)(W + 20480000);
  unsigned short* aggT = (unsigned short*)(W + 40960000);
  unsigned short* hB   = (unsigned short*)(W + 61440000);
  unsigned short* WA   = (unsigned short*)(W + 81920000);    // 262,144 B
  unsigned short* Wall = (unsigned short*)(W + 82182144);    // 1,048,576 B
  float* biasP   = (float*)(W + 83230720);                   // 4,096 B
  int* deg       = (int*)(W + 83234816);
  int* row_start = (int*)(W + 83255296);
  int* cursor    = (int*)(W + 83275776);
  int* csr       = (int*)(W + 83296256);                     // 640,000 B
  float* inv_deg = (float*)(W + 83936256);

  zero_int2<<<(N_ + 255)/256, 256, 0, stream>>>(deg, cursor, N_);
  convert_weights<<<2564, 256, 0, stream>>>(wA, wFc, wGc, wZ, wFh,
                                            bFc, bGc, bZ, bFh, WA, Wall, biasP);
  convert_u<<<M_/4, 256, 0, stream>>>(u, cB, hT);
  hist_kernel<<<E_/256, 256, 0, stream>>>(dst, deg);
  scan_kernel<<<1, 256, 0, stream>>>(deg, row_start, inv_deg);
  fill_kernel<<<E_/256, 256, 0, stream>>>(src, dst, row_start, cursor, csr);
  gather_kernel<<<M_/4, 256, 0, stream>>>(hT, csr, row_start, inv_deg, aggT);
  gemm1_kernel<<<M_/64, 256, 0, stream>>>(hT, aggT, WA, bA, hB);
  dim3 g2(M_/64, 4);
  gemm_big_kernel<<<g2, 256, 0, stream>>>(cB, hB, Wall, biasP, act);
  epilogue_kernel<<<M_/4, 256, 0, stream>>>(act, u, out);
}

// Round 3
// 582.932 us; speedup vs baseline: 1.3520x; 1.1668x over previous
//
#include <hip/hip_runtime.h>
#include <math.h>

// Problem constants
#define B_ 8
#define N_ 5000
#define E_ 160000
#define M_ 40000      // N_*B_ rows, r = n*B_ + b
#define K_ 512

typedef __bf16 v8bf __attribute__((ext_vector_type(8)));
typedef float  v4f  __attribute__((ext_vector_type(4)));
typedef unsigned short u16x4v __attribute__((ext_vector_type(4)));

__device__ __forceinline__ unsigned short f2b(float f){
  unsigned int u = __builtin_bit_cast(unsigned int, f);
  u += 0x7FFFu + ((u >> 16) & 1u);          // round-to-nearest-even
  return (unsigned short)(u >> 16);
}
__device__ __forceinline__ float b2f(unsigned short s){
  return __builtin_bit_cast(float, ((unsigned int)s) << 16);
}
__device__ __forceinline__ float softplus_(float x){
  return (x > 15.0f) ? x : log1pf(__expf(x));
}
__device__ __forceinline__ float tanh_(float x){
  // 1 - 2/(e^{2x}+1): e=inf -> 1, e=0 -> -1, no NaN
  float e = __expf(2.0f*x);
  return 1.0f - 2.0f/(e + 1.0f);
}

// ---------------- setup kernels ----------------

__global__ __launch_bounds__(256) void zero_int2(int* a, int* b, int n){
  int i = blockIdx.x*256 + threadIdx.x;
  if (i < n){ a[i] = 0; b[i] = 0; }
}

// 5 * 131072 weight elems + 1024 packed bias. m: 0->WA, 1..4->Wall rows [Fc;Gc;Z;Fh]
__global__ __launch_bounds__(256) void convert_weights(
    const float* __restrict__ wA, const float* __restrict__ wFc,
    const float* __restrict__ wGc, const float* __restrict__ wZ,
    const float* __restrict__ wFh,
    const float* __restrict__ bFc, const float* __restrict__ bGc,
    const float* __restrict__ bZ,  const float* __restrict__ bFh,
    unsigned short* __restrict__ WA, unsigned short* __restrict__ Wall,
    float* __restrict__ biasP)
{
  int idx = blockIdx.x*256 + threadIdx.x;      // < 656384
  if (idx >= 655360){
    int j = idx - 655360;                      // 0..1023
    int mat = j >> 8, jj = j & 255;
    const float* bp = (mat == 0) ? bFc : (mat == 1) ? bGc : (mat == 2) ? bZ : bFh;
    biasP[j] = bp[jj];
    return;
  }
  int m = idx >> 17;                           // 131072 = 2^17
  int i = idx & 131071;
  float v;
  if      (m == 0) v = wA[i];
  else if (m == 1) v = wFc[i];
  else if (m == 2) v = wGc[i];
  else if (m == 3) v = wZ[i];
  else             v = wFh[i];
  unsigned short o = f2b(v);
  if (m == 0) WA[i] = o;
  else        Wall[(m-1)*131072 + i] = o;
}

// u (B,N,512) fp32 -> cB[r*256+q] bf16 (c part), hT[r*256+q] bf16 (h part), r=n*B+b
__global__ __launch_bounds__(256) void convert_u(
    const float* __restrict__ u, unsigned short* __restrict__ cB,
    unsigned short* __restrict__ hT)
{
  int r = blockIdx.x*4 + (threadIdx.x >> 6);
  int l = threadIdx.x & 63;
  int n = r >> 3, b = r & 7;
  const float* up = u + (size_t)(b*N_ + n)*512 + l*4;
  float4 cf = *(const float4*)up;
  float4 hf = *(const float4*)(up + 256);
  u16x4v c4, h4;
  c4.x = f2b(cf.x); c4.y = f2b(cf.y); c4.z = f2b(cf.z); c4.w = f2b(cf.w);
  h4.x = f2b(hf.x); h4.y = f2b(hf.y); h4.z = f2b(hf.z); h4.w = f2b(hf.w);
  *(u16x4v*)(cB + (size_t)r*256 + l*4) = c4;
  *(u16x4v*)(hT + (size_t)r*256 + l*4) = h4;
}

// ---------------- CSR build ----------------

__global__ __launch_bounds__(256) void hist_kernel(const int* __restrict__ dst, int* __restrict__ deg){
  int e = blockIdx.x*256 + threadIdx.x;   // exactly E_
  atomicAdd(&deg[dst[e]], 1);
}

__global__ __launch_bounds__(256) void scan_kernel(
    const int* __restrict__ deg, int* __restrict__ row_start, float* __restrict__ inv_deg)
{
  __shared__ int sums[256];
  int t = threadIdx.x;
  int base = t*20;
  int cnt[20];
  int local = 0;
#pragma unroll
  for (int i = 0; i < 20; ++i){
    int n = base + i;
    int d = (n < N_) ? deg[n] : 0;
    cnt[i] = d; local += d;
  }
  sums[t] = local; __syncthreads();
  for (int s = 1; s < 256; s <<= 1){
    int v = (t >= s) ? sums[t - s] : 0;
    __syncthreads();
    sums[t] += v;
    __syncthreads();
  }
  int prefix = (t == 0) ? 0 : sums[t-1];
#pragma unroll
  for (int i = 0; i < 20; ++i){
    int n = base + i;
    if (n < N_){
      row_start[n] = prefix;
      int d = cnt[i];
      inv_deg[n] = 1.0f / (float)((d > 1) ? d : 1);
      prefix += d;
    }
  }
  if (t == 255) row_start[N_] = prefix;
}

__global__ __launch_bounds__(256) void fill_kernel(
    const int* __restrict__ src, const int* __restrict__ dst,
    const int* __restrict__ row_start, int* __restrict__ cursor, int* __restrict__ csr)
{
  int e = blockIdx.x*256 + threadIdx.x;
  int d = dst[e];
  int p = atomicAdd(&cursor[d], 1);
  csr[row_start[d] + p] = src[e];
}

// one wave per r=(n,b): agg[r,q] = mean over edges dst==n of h[b,src,q]
__global__ __launch_bounds__(256) void gather_kernel(
    const unsigned short* __restrict__ hT, const int* __restrict__ csr,
    const int* __restrict__ row_start, const float* __restrict__ inv_deg,
    unsigned short* __restrict__ aggT)
{
  int r = blockIdx.x*4 + (threadIdx.x >> 6);
  int l = threadIdx.x & 63;
  int n = r >> 3, b = r & 7;
  int e0 = row_start[n], e1 = row_start[n+1];
  float a0 = 0.f, a1 = 0.f, a2 = 0.f, a3 = 0.f;
  const unsigned short* base = hT + b*256 + l*4;
  for (int e = e0; e < e1; ++e){
    int s = csr[e];
    u16x4v hv = *(const u16x4v*)(base + (size_t)s*2048);
    a0 += b2f(hv.x); a1 += b2f(hv.y); a2 += b2f(hv.z); a3 += b2f(hv.w);
  }
  float inv = inv_deg[n];
  u16x4v o;
  o.x = f2b(a0*inv); o.y = f2b(a1*inv); o.z = f2b(a2*inv); o.w = f2b(a3*inv);
  *(u16x4v*)(aggT + (size_t)r*256 + l*4) = o;
}

// ---------------- tiled GEMM (m97 structure) ----------------
// C[m, n] = act( [A0|A1](m, 0:512) . Bw(n, 0:512) + bias[n] )
// 128x128 tile, 4 waves (2x2 of 64x64), BK=64, global_load_lds staging with
// XOR-chunk swizzle on the GLOBAL address (LDS slots stay lane-contiguous as
// global_load_lds requires; fragment ds_read_b128 becomes bank-conflict-free).
// MODE 0: gemm1 -> dst[r*256 + col], softplus.  Bw row stride 512.
// MODE 1: gemm_big -> act[(b*N+n)*1024 + col], tanh on slab y>>1==2.
// Store guard r < M_ handles the 40000 % 128 remainder; staging over-reads
// land in adjacent ws buffers (harmless garbage).

template<int MODE>
__global__ __launch_bounds__(256) void gemm_tiled(
    const unsigned short* __restrict__ A0, const unsigned short* __restrict__ A1,
    const unsigned short* __restrict__ Bw, const float* __restrict__ bias,
    unsigned short* dstp)
{
  __shared__ unsigned short lds[17408];       // staging: 2x(128x64); epilogue: 128x136
  unsigned short* lA = lds;
  unsigned short* lB = lds + 8192;

  const int tid = threadIdx.x;
  const int w  = tid >> 6, l = tid & 63;
  const int wr = w >> 1,  wc = w & 1;
  const int lq = l >> 4,  lr = l & 15;
  const int m0 = blockIdx.x * 128;
  const int n0 = blockIdx.y * 128;

  // staging constants: per issue of 32 rows, thread covers row (tid>>3),
  // fetching global 16B chunk ((tid&7) ^ (row&7)) into LDS slot (tid&7).
  const int srow   = tid >> 3;                 // 0..31
  const int schunk = (tid & 7) ^ (srow & 7);   // swizzled k-chunk

  v4f acc[4][4] = {};
#pragma unroll 1
  for (int kb = 0; kb < 8; ++kb){
    const unsigned short* As = (kb < 4) ? A0 : A1;
    const int ak = (kb & 3) * 64;
    __syncthreads();
#pragma unroll
    for (int i = 0; i < 4; ++i){
      const int row = i*32 + srow;
      const unsigned short* gpA = As + (size_t)(m0 + row)*256 + ak + schunk*8;
      const unsigned short* gpB = Bw + (size_t)(n0 + row)*512 + kb*64 + schunk*8;
      unsigned short* lpA = lA + (i*32 + w*8)*64;
      unsigned short* lpB = lB + (i*32 + w*8)*64;
      __builtin_amdgcn_global_load_lds((const __attribute__((address_space(1))) void*)gpA,
                                       (__attribute__((address_space(3))) void*)lpA, 16, 0, 0);
      __builtin_amdgcn_global_load_lds((const __attribute__((address_space(1))) void*)gpB,
                                       (__attribute__((address_space(3))) void*)lpB, 16, 0, 0);
    }
    __syncthreads();
#pragma unroll
    for (int ks = 0; ks < 2; ++ks){
      v8bf a[4], b[4];
#pragma unroll
      for (int rt = 0; rt < 4; ++rt){
        const int ar = wr*64 + rt*16 + lr;
        a[rt] = *(const v8bf*)(lA + ar*64 + (((ks*4 + lq) ^ (ar & 7)))*8);
      }
#pragma unroll
      for (int ct = 0; ct < 4; ++ct){
        const int br = wc*64 + ct*16 + lr;
        b[ct] = *(const v8bf*)(lB + br*64 + (((ks*4 + lq) ^ (br & 7)))*8);
      }
#pragma unroll
      for (int rt = 0; rt < 4; ++rt)
#pragma unroll
        for (int ct = 0; ct < 4; ++ct)
          acc[rt][ct] = __builtin_amdgcn_mfma_f32_16x16x32_bf16(a[rt], b[ct], acc[rt][ct], 0, 0, 0);
    }
  }

  float bv[4];
#pragma unroll
  for (int ct = 0; ct < 4; ++ct) bv[ct] = bias[n0 + wc*64 + ct*16 + lr];

  const bool is_tanh = (MODE == 1) && ((blockIdx.y >> 1) == 2);

  __syncthreads();   // done reading lA/lB; reuse as output repack buffer
#pragma unroll
  for (int rt = 0; rt < 4; ++rt){
#pragma unroll
    for (int ct = 0; ct < 4; ++ct){
      const int col = wc*64 + ct*16 + lr;
#pragma unroll
      for (int reg = 0; reg < 4; ++reg){
        const int row = wr*64 + rt*16 + lq*4 + reg;
        const float x = acc[rt][ct][reg] + bv[ct];
        const float v = is_tanh ? tanh_(x) : softplus_(x);
        lds[row*136 + col] = f2b(v);
      }
    }
  }
  __syncthreads();

  // coalesced store: 8 issues, each row gets 16 lanes x 16B = 256B contiguous
#pragma unroll
  for (int i = 0; i < 8; ++i){
    const int row = i*16 + (tid >> 4);
    const int r = m0 + row;
    if (r < M_){
      const uint4 v = *(const uint4*)(lds + row*136 + (tid & 15)*8);
      if (MODE == 0){
        *(uint4*)(dstp + (size_t)r*256 + n0 + (tid & 15)*8) = v;
      } else {
        const int n = r >> 3, b = r & 7;
        *(uint4*)(dstp + ((size_t)b*N_ + n)*1024 + n0 + (tid & 15)*8) = v;
      }
    }
  }
}

// ---------------- epilogue: dc with projection + dh ----------------
// One wave per row r. act aliases out (same row region) — reads complete before
// stores within the wave; no __restrict__ so the compiler keeps the order.

__global__ __launch_bounds__(256) void epilogue_kernel(
    const unsigned short* act, const float* __restrict__ u, float* out)
{
  int r = blockIdx.x*4 + (threadIdx.x >> 6);
  int l = threadIdx.x & 63;
  int n = r >> 3, b = r & 7;
  const size_t rr = (size_t)(b*N_ + n);
  const unsigned short* arow = act + rr*1024;
  const float* urow = u + rr*512;
  float* orow = out + rr*512;

  u16x4v fc4 = *(const u16x4v*)(arow +        l*4);
  u16x4v gc4 = *(const u16x4v*)(arow + 256 +  l*4);
  u16x4v z4  = *(const u16x4v*)(arow + 512 +  l*4);
  u16x4v fh4 = *(const u16x4v*)(arow + 768 +  l*4);
  float4 c4f = *(const float4*)(urow + l*4);
  float4 h4f = *(const float4*)(urow + 256 + l*4);

  float c[4] = {c4f.x, c4f.y, c4f.z, c4f.w};
  float h[4] = {h4f.x, h4f.y, h4f.z, h4f.w};
  float dc[4], fh[4];
  float num = 0.f, den = 0.f;
#pragma unroll
  for (int i = 0; i < 4; ++i){
    float fc = b2f(fc4[i]), gc = b2f(gc4[i]), z = b2f(z4[i]);
    fh[i] = b2f(fh4[i]);
    dc[i] = -fc*c[i] + gc*z;
    num += dc[i]*c[i];
    den += c[i]*c[i];
  }
#pragma unroll
  for (int s = 1; s < 64; s <<= 1){
    num += __shfl_xor(num, s, 64);
    den += __shfl_xor(den, s, 64);
  }
  const float proj = num / den;

  float4 o, oh;
  o.x = dc[0] - proj*c[0]; o.y = dc[1] - proj*c[1];
  o.z = dc[2] - proj*c[2]; o.w = dc[3] - proj*c[3];
  oh.x = -fh[0]*h[0]; oh.y = -fh[1]*h[1];
  oh.z = -fh[2]*h[2]; oh.w = -fh[3]*h[3];
  *(float4*)(orow + l*4) = o;
  *(float4*)(orow + 256 + l*4) = oh;
}

// ---------------- launch ----------------

extern "C" void kernel_launch(void* const* d_in, const int* in_sizes, int n_in,
                              void* d_out, int out_size, void* d_ws, size_t ws_size,
                              hipStream_t stream) {
  const float* u    = (const float*)d_in[0];
  const int*   src  = (const int*)d_in[1];
  const int*   dst  = (const int*)d_in[2];
  const float* wFc  = (const float*)d_in[4];
  const float* bFc  = (const float*)d_in[5];
  const float* wFh  = (const float*)d_in[6];
  const float* bFh  = (const float*)d_in[7];
  const float* wGc  = (const float*)d_in[8];
  const float* bGc  = (const float*)d_in[9];
  const float* wZ   = (const float*)d_in[10];
  const float* bZ   = (const float*)d_in[11];
  const float* wA   = (const float*)d_in[12];
  const float* bA   = (const float*)d_in[13];
  float* out = (float*)d_out;
  unsigned short* act = (unsigned short*)d_out;   // bf16 activations overlay out

  // ws layout. GEMM staging over-reads up to 63 rows (32,256 B) past the end of
  // hT/cB/aggT/hB — each overflow lands in the NEXT allocation (readable garbage,
  // results discarded by the r < M_ store guard). Keep this buffer order.
  char* W = (char*)d_ws;
  unsigned short* hT   = (unsigned short*)(W + 0);           // 20,480,000 B
  unsigned short* cB   = (unsigned short*)(W + 20480000);
  unsigned short* aggT = (unsigned short*)(W + 40960000);
  unsigned short* hB   = (unsigned short*)(W + 61440000);
  unsigned short* WA   = (unsigned short*)(W + 81920000);    // 262,144 B
  unsigned short* Wall = (unsigned short*)(W + 82182144);    // 1,048,576 B
  float* biasP   = (float*)(W + 83230720);                   // 4,096 B
  int* deg       = (int*)(W + 83234816);
  int* row_start = (int*)(W + 83255296);
  int* cursor    = (int*)(W + 83275776);
  int* csr       = (int*)(W + 83296256);                     // 640,000 B
  float* inv_deg = (float*)(W + 83936256);

  zero_int2<<<(N_ + 255)/256, 256, 0, stream>>>(deg, cursor, N_);
  convert_weights<<<2564, 256, 0, stream>>>(wA, wFc, wGc, wZ, wFh,
                                            bFc, bGc, bZ, bFh, WA, Wall, biasP);
  convert_u<<<M_/4, 256, 0, stream>>>(u, cB, hT);
  hist_kernel<<<E_/256, 256, 0, stream>>>(dst, deg);
  scan_kernel<<<1, 256, 0, stream>>>(deg, row_start, inv_deg);
  fill_kernel<<<E_/256, 256, 0, stream>>>(src, dst, row_start, cursor, csr);
  gather_kernel<<<M_/4, 256, 0, stream>>>(hT, csr, row_start, inv_deg, aggT);

  dim3 g1((M_ + 127)/128, 2);
  gemm_tiled<0><<<g1, 256, 0, stream>>>(hT, aggT, WA, bA, hB);
  dim3 g2((M_ + 127)/128, 8);
  gemm_tiled<1><<<g2, 256, 0, stream>>>(cB, hB, Wall, biasP, act);

  epilogue_kernel<<<M_/4, 256, 0, stream>>>(act, u, out);
}

// Round 4
// 425.405 us; speedup vs baseline: 1.8527x; 1.3703x over previous
//
#include <hip/hip_runtime.h>
#include <math.h>

// Problem constants
#define B_ 8
#define N_ 5000
#define E_ 160000
#define M_ 40000      // N_*B_ rows, r = n*B_ + b
#define K_ 512
#define XT_ 313       // (M_+127)/128 row tiles

typedef __bf16 v8bf __attribute__((ext_vector_type(8)));
typedef float  v4f  __attribute__((ext_vector_type(4)));
typedef unsigned short u16x4v __attribute__((ext_vector_type(4)));
typedef unsigned short u16x8v __attribute__((ext_vector_type(8)));

__device__ __forceinline__ unsigned short f2b(float f){
  unsigned int u = __builtin_bit_cast(unsigned int, f);
  u += 0x7FFFu + ((u >> 16) & 1u);          // round-to-nearest-even
  return (unsigned short)(u >> 16);
}
__device__ __forceinline__ float b2f(unsigned short s){
  return __builtin_bit_cast(float, ((unsigned int)s) << 16);
}
__device__ __forceinline__ float softplus_(float x){
  // HW v_exp/v_log; x>15 -> x (exp overflow guard); bf16 output absorbs ~1e-6 err
  return (x > 15.0f) ? x : __logf(1.0f + __expf(x));
}
__device__ __forceinline__ float tanh_(float x){
  float e = __expf(2.0f*x);
  return 1.0f - 2.0f/(e + 1.0f);
}

// ---------------- setup kernels ----------------

__global__ __launch_bounds__(256) void zero_int2(int* a, int* b, int n){
  int i = blockIdx.x*256 + threadIdx.x;
  if (i < n){ a[i] = 0; b[i] = 0; }
}

// 5 * 131072 weight elems + 1024 packed bias. m: 0->WA, 1..4->Wall rows [Fc;Gc;Z;Fh]
__global__ __launch_bounds__(256) void convert_weights(
    const float* __restrict__ wA, const float* __restrict__ wFc,
    const float* __restrict__ wGc, const float* __restrict__ wZ,
    const float* __restrict__ wFh,
    const float* __restrict__ bFc, const float* __restrict__ bGc,
    const float* __restrict__ bZ,  const float* __restrict__ bFh,
    unsigned short* __restrict__ WA, unsigned short* __restrict__ Wall,
    float* __restrict__ biasP)
{
  int idx = blockIdx.x*256 + threadIdx.x;      // < 656384
  if (idx >= 655360){
    int j = idx - 655360;                      // 0..1023
    int mat = j >> 8, jj = j & 255;
    const float* bp = (mat == 0) ? bFc : (mat == 1) ? bGc : (mat == 2) ? bZ : bFh;
    biasP[j] = bp[jj];
    return;
  }
  int m = idx >> 17;                           // 131072 = 2^17
  int i = idx & 131071;
  float v;
  if      (m == 0) v = wA[i];
  else if (m == 1) v = wFc[i];
  else if (m == 2) v = wGc[i];
  else if (m == 3) v = wZ[i];
  else             v = wFh[i];
  unsigned short o = f2b(v);
  if (m == 0) WA[i] = o;
  else        Wall[(m-1)*131072 + i] = o;
}

// u (B,N,512) fp32 -> cB[r*256+q] bf16 (c part), hT[r*256+q] bf16 (h part), r=n*B+b
__global__ __launch_bounds__(256) void convert_u(
    const float* __restrict__ u, unsigned short* __restrict__ cB,
    unsigned short* __restrict__ hT)
{
  int r = blockIdx.x*4 + (threadIdx.x >> 6);
  int l = threadIdx.x & 63;
  int n = r >> 3, b = r & 7;
  const float* up = u + (size_t)(b*N_ + n)*512 + l*4;
  float4 cf = *(const float4*)up;
  float4 hf = *(const float4*)(up + 256);
  u16x4v c4, h4;
  c4.x = f2b(cf.x); c4.y = f2b(cf.y); c4.z = f2b(cf.z); c4.w = f2b(cf.w);
  h4.x = f2b(hf.x); h4.y = f2b(hf.y); h4.z = f2b(hf.z); h4.w = f2b(hf.w);
  *(u16x4v*)(cB + (size_t)r*256 + l*4) = c4;
  *(u16x4v*)(hT + (size_t)r*256 + l*4) = h4;
}

// ---------------- CSR build ----------------

__global__ __launch_bounds__(256) void hist_kernel(const int* __restrict__ dst, int* __restrict__ deg){
  int e = blockIdx.x*256 + threadIdx.x;   // exactly E_
  atomicAdd(&deg[dst[e]], 1);
}

__global__ __launch_bounds__(256) void scan_kernel(
    const int* __restrict__ deg, int* __restrict__ row_start, float* __restrict__ inv_deg)
{
  __shared__ int sums[256];
  int t = threadIdx.x;
  int base = t*20;
  int cnt[20];
  int local = 0;
#pragma unroll
  for (int i = 0; i < 20; ++i){
    int n = base + i;
    int d = (n < N_) ? deg[n] : 0;
    cnt[i] = d; local += d;
  }
  sums[t] = local; __syncthreads();
  for (int s = 1; s < 256; s <<= 1){
    int v = (t >= s) ? sums[t - s] : 0;
    __syncthreads();
    sums[t] += v;
    __syncthreads();
  }
  int prefix = (t == 0) ? 0 : sums[t-1];
#pragma unroll
  for (int i = 0; i < 20; ++i){
    int n = base + i;
    if (n < N_){
      row_start[n] = prefix;
      int d = cnt[i];
      inv_deg[n] = 1.0f / (float)((d > 1) ? d : 1);
      prefix += d;
    }
  }
  if (t == 255) row_start[N_] = prefix;
}

__global__ __launch_bounds__(256) void fill_kernel(
    const int* __restrict__ src, const int* __restrict__ dst,
    const int* __restrict__ row_start, int* __restrict__ cursor, int* __restrict__ csr)
{
  int e = blockIdx.x*256 + threadIdx.x;
  int d = dst[e];
  int p = atomicAdd(&cursor[d], 1);
  csr[row_start[d] + p] = src[e];
}

// one BLOCK per node n: 256 threads cover 8 batches x 32 col-segments.
// Per edge the whole block reads one contiguous 4 KB run of hT (rows s*8..s*8+7),
// csr[e] is a uniform scalar load. 2-edge unroll for memory-level parallelism.
__global__ __launch_bounds__(256) void gather_n_kernel(
    const unsigned short* __restrict__ hT, const int* __restrict__ csr,
    const int* __restrict__ row_start, const float* __restrict__ inv_deg,
    unsigned short* __restrict__ aggT)
{
  const int n = blockIdx.x;
  const int tid = threadIdx.x;
  const int boff = (tid >> 5)*256 + (tid & 31)*8;   // b*256 + cs*8 (shorts)
  const int e0 = row_start[n], e1 = row_start[n+1];

  float acc[8] = {};
  int e = e0;
  for (; e + 1 < e1; e += 2){
    int s0 = csr[e], s1 = csr[e+1];
    u16x8v v0 = *(const u16x8v*)(hT + (size_t)s0*2048 + boff);
    u16x8v v1 = *(const u16x8v*)(hT + (size_t)s1*2048 + boff);
#pragma unroll
    for (int i = 0; i < 8; ++i) acc[i] += b2f(v0[i]) + b2f(v1[i]);
  }
  if (e < e1){
    int s0 = csr[e];
    u16x8v v0 = *(const u16x8v*)(hT + (size_t)s0*2048 + boff);
#pragma unroll
    for (int i = 0; i < 8; ++i) acc[i] += b2f(v0[i]);
  }
  const float inv = inv_deg[n];
  u16x8v o;
#pragma unroll
  for (int i = 0; i < 8; ++i) o[i] = f2b(acc[i]*inv);
  *(u16x8v*)(aggT + (size_t)n*2048 + boff) = o;
}

// ---------------- tiled GEMM (m97 structure + same-XCD y-grouping) ----------------
// C[m, n] = act( [A0|A1](m, 0:512) . Bw(n, 0:512) + bias[n] )
// 128x128 tile, 4 waves (2x2 of 64x64), BK=64, global_load_lds staging with
// XOR-chunk swizzle on the GLOBAL address (LDS slots stay lane-contiguous as
// global_load_lds requires; fragment ds_read_b128 becomes bank-conflict-free).
// 1-D grid, id decode groups all NY col-slab blocks of one row-tile x into a
// 64-id window with id % 8 == const -> same XCD under round-robin dispatch ->
// the A row-tile is fetched from HBM once and L2 serves the other NY-1 reads.
// MODE 0 (NY=2): gemm1 -> dst[r*256 + col], softplus.
// MODE 1 (NY=8): gemm_big -> act[(b*N+n)*1024 + col], tanh on slab y>>1==2.

template<int MODE>
__global__ __launch_bounds__(256) void gemm_tiled(
    const unsigned short* __restrict__ A0, const unsigned short* __restrict__ A1,
    const unsigned short* __restrict__ Bw, const float* __restrict__ bias,
    unsigned short* dstp)
{
  const int id = blockIdx.x;
  int x, y;
  if (MODE == 1){
    const int u6 = id & 63;
    y = u6 >> 3;
    x = (id >> 6)*8 + (u6 & 7);
  } else {
    const int u4 = id & 15;
    y = u4 >> 3;
    x = (id >> 4)*8 + (u4 & 7);
  }
  if (x >= XT_) return;

  __shared__ unsigned short lds[17408];       // staging: 2x(128x64); epilogue: 128x136
  unsigned short* lA = lds;
  unsigned short* lB = lds + 8192;

  const int tid = threadIdx.x;
  const int w  = tid >> 6, l = tid & 63;
  const int wr = w >> 1,  wc = w & 1;
  const int lq = l >> 4,  lr = l & 15;
  const int m0 = x * 128;
  const int n0 = y * 128;

  // staging: per issue of 32 rows, thread covers row (tid>>3),
  // fetching global 16B chunk ((tid&7) ^ (row&7)) into LDS slot (tid&7).
  const int srow   = tid >> 3;                 // 0..31
  const int schunk = (tid & 7) ^ (srow & 7);   // swizzled k-chunk

  v4f acc[4][4] = {};
#pragma unroll 1
  for (int kb = 0; kb < 8; ++kb){
    const unsigned short* As = (kb < 4) ? A0 : A1;
    const int ak = (kb & 3) * 64;
    __syncthreads();
#pragma unroll
    for (int i = 0; i < 4; ++i){
      const int row = i*32 + srow;
      const unsigned short* gpA = As + (size_t)(m0 + row)*256 + ak + schunk*8;
      const unsigned short* gpB = Bw + (size_t)(n0 + row)*512 + kb*64 + schunk*8;
      unsigned short* lpA = lA + (i*32 + w*8)*64;
      unsigned short* lpB = lB + (i*32 + w*8)*64;
      __builtin_amdgcn_global_load_lds((const __attribute__((address_space(1))) void*)gpA,
                                       (__attribute__((address_space(3))) void*)lpA, 16, 0, 0);
      __builtin_amdgcn_global_load_lds((const __attribute__((address_space(1))) void*)gpB,
                                       (__attribute__((address_space(3))) void*)lpB, 16, 0, 0);
    }
    __syncthreads();
#pragma unroll
    for (int ks = 0; ks < 2; ++ks){
      v8bf a[4], b[4];
#pragma unroll
      for (int rt = 0; rt < 4; ++rt){
        const int ar = wr*64 + rt*16 + lr;
        a[rt] = *(const v8bf*)(lA + ar*64 + (((ks*4 + lq) ^ (ar & 7)))*8);
      }
#pragma unroll
      for (int ct = 0; ct < 4; ++ct){
        const int br = wc*64 + ct*16 + lr;
        b[ct] = *(const v8bf*)(lB + br*64 + (((ks*4 + lq) ^ (br & 7)))*8);
      }
#pragma unroll
      for (int rt = 0; rt < 4; ++rt)
#pragma unroll
        for (int ct = 0; ct < 4; ++ct)
          acc[rt][ct] = __builtin_amdgcn_mfma_f32_16x16x32_bf16(a[rt], b[ct], acc[rt][ct], 0, 0, 0);
    }
  }

  float bv[4];
#pragma unroll
  for (int ct = 0; ct < 4; ++ct) bv[ct] = bias[n0 + wc*64 + ct*16 + lr];

  const bool is_tanh = (MODE == 1) && ((y >> 1) == 2);

  __syncthreads();   // done reading lA/lB; reuse as output repack buffer
#pragma unroll
  for (int rt = 0; rt < 4; ++rt){
#pragma unroll
    for (int ct = 0; ct < 4; ++ct){
      const int col = wc*64 + ct*16 + lr;
#pragma unroll
      for (int reg = 0; reg < 4; ++reg){
        const int row = wr*64 + rt*16 + lq*4 + reg;
        const float xv = acc[rt][ct][reg] + bv[ct];
        const float v = is_tanh ? tanh_(xv) : softplus_(xv);
        lds[row*136 + col] = f2b(v);
      }
    }
  }
  __syncthreads();

  // coalesced store: 8 issues, each row gets 16 lanes x 16B = 256B contiguous
#pragma unroll
  for (int i = 0; i < 8; ++i){
    const int row = i*16 + (tid >> 4);
    const int r = m0 + row;
    if (r < M_){
      const uint4 v = *(const uint4*)(lds + row*136 + (tid & 15)*8);
      if (MODE == 0){
        *(uint4*)(dstp + (size_t)r*256 + n0 + (tid & 15)*8) = v;
      } else {
        const int n = r >> 3, b = r & 7;
        *(uint4*)(dstp + ((size_t)b*N_ + n)*1024 + n0 + (tid & 15)*8) = v;
      }
    }
  }
}

// ---------------- epilogue: dc with projection + dh ----------------
// One wave per row r. act aliases out (same row region) — reads complete before
// stores within the wave; no __restrict__ so the compiler keeps the order.

__global__ __launch_bounds__(256) void epilogue_kernel(
    const unsigned short* act, const float* __restrict__ u, float* out)
{
  int r = blockIdx.x*4 + (threadIdx.x >> 6);
  int l = threadIdx.x & 63;
  int n = r >> 3, b = r & 7;
  const size_t rr = (size_t)(b*N_ + n);
  const unsigned short* arow = act + rr*1024;
  const float* urow = u + rr*512;
  float* orow = out + rr*512;

  u16x4v fc4 = *(const u16x4v*)(arow +        l*4);
  u16x4v gc4 = *(const u16x4v*)(arow + 256 +  l*4);
  u16x4v z4  = *(const u16x4v*)(arow + 512 +  l*4);
  u16x4v fh4 = *(const u16x4v*)(arow + 768 +  l*4);
  float4 c4f = *(const float4*)(urow + l*4);
  float4 h4f = *(const float4*)(urow + 256 + l*4);

  float c[4] = {c4f.x, c4f.y, c4f.z, c4f.w};
  float h[4] = {h4f.x, h4f.y, h4f.z, h4f.w};
  float dc[4], fh[4];
  float num = 0.f, den = 0.f;
#pragma unroll
  for (int i = 0; i < 4; ++i){
    float fc = b2f(fc4[i]), gc = b2f(gc4[i]), z = b2f(z4[i]);
    fh[i] = b2f(fh4[i]);
    dc[i] = -fc*c[i] + gc*z;
    num += dc[i]*c[i];
    den += c[i]*c[i];
  }
#pragma unroll
  for (int s = 1; s < 64; s <<= 1){
    num += __shfl_xor(num, s, 64);
    den += __shfl_xor(den, s, 64);
  }
  const float proj = num / den;

  float4 o, oh;
  o.x = dc[0] - proj*c[0]; o.y = dc[1] - proj*c[1];
  o.z = dc[2] - proj*c[2]; o.w = dc[3] - proj*c[3];
  oh.x = -fh[0]*h[0]; oh.y = -fh[1]*h[1];
  oh.z = -fh[2]*h[2]; oh.w = -fh[3]*h[3];
  *(float4*)(orow + l*4) = o;
  *(float4*)(orow + 256 + l*4) = oh;
}

// ---------------- launch ----------------

extern "C" void kernel_launch(void* const* d_in, const int* in_sizes, int n_in,
                              void* d_out, int out_size, void* d_ws, size_t ws_size,
                              hipStream_t stream) {
  const float* u    = (const float*)d_in[0];
  const int*   src  = (const int*)d_in[1];
  const int*   dst  = (const int*)d_in[2];
  const float* wFc  = (const float*)d_in[4];
  const float* bFc  = (const float*)d_in[5];
  const float* wFh  = (const float*)d_in[6];
  const float* bFh  = (const float*)d_in[7];
  const float* wGc  = (const float*)d_in[8];
  const float* bGc  = (const float*)d_in[9];
  const float* wZ   = (const float*)d_in[10];
  const float* bZ   = (const float*)d_in[11];
  const float* wA   = (const float*)d_in[12];
  const float* bA   = (const float*)d_in[13];
  float* out = (float*)d_out;
  unsigned short* act = (unsigned short*)d_out;   // bf16 activations overlay out

  // ws layout. GEMM staging over-reads up to 64 rows past the end of
  // hT/cB/aggT/hB — each overflow lands in the NEXT allocation (readable garbage,
  // results discarded by the r < M_ store guard). Keep this buffer order.
  char* W = (char*)d_ws;
  unsigned short* hT   = (unsigned short*)(W + 0);           // 20,480,000 B
  unsigned short* cB   = (unsigned short*)(W + 20480000);
  unsigned short* aggT = (unsigned short*)(W + 40960000);
  unsigned short* hB   = (unsigned short*)(W + 61440000);
  unsigned short* WA   = (unsigned short*)(W + 81920000);    // 262,144 B
  unsigned short* Wall = (unsigned short*)(W + 82182144);    // 1,048,576 B
  float* biasP   = (float*)(W + 83230720);                   // 4,096 B
  int* deg       = (int*)(W + 83234816);
  int* row_start = (int*)(W + 83255296);
  int* cursor    = (int*)(W + 83275776);
  int* csr       = (int*)(W + 83296256);                     // 640,000 B
  float* inv_deg = (float*)(W + 83936256);

  zero_int2<<<(N_ + 255)/256, 256, 0, stream>>>(deg, cursor, N_);
  convert_weights<<<2564, 256, 0, stream>>>(wA, wFc, wGc, wZ, wFh,
                                            bFc, bGc, bZ, bFh, WA, Wall, biasP);
  convert_u<<<M_/4, 256, 0, stream>>>(u, cB, hT);
  hist_kernel<<<E_/256, 256, 0, stream>>>(dst, deg);
  scan_kernel<<<1, 256, 0, stream>>>(deg, row_start, inv_deg);
  fill_kernel<<<E_/256, 256, 0, stream>>>(src, dst, row_start, cursor, csr);
  gather_n_kernel<<<N_, 256, 0, stream>>>(hT, csr, row_start, inv_deg, aggT);

  // 1-D swizzled grids: 40 g-groups of 8 x-tiles (x<313 guard inside)
  gemm_tiled<0><<<40*16, 256, 0, stream>>>(hT, aggT, WA, bA, hB);
  gemm_tiled<1><<<40*64, 256, 0, stream>>>(cB, hB, Wall, biasP, act);

  epilogue_kernel<<<M_/4, 256, 0, stream>>>(act, u, out);
}